// Round 2
// baseline (28969.476 us; speedup 1.0000x reference)
//
#include <hip/hip_runtime.h>

// Per-channel LSTM (input_size=1) + per-channel Linear(H,1), fully fused.
// B=512, T=1024, C=64, H=128.
// Round 2: grid=512 (64-row batch tiles) -> 2 blocks/CU so independent blocks
// overlap MFMA/VALU/barrier phases. XOR bank swizzle on h-layout. SGPR-based
// x addressing with same-register prefetch across the barrier. t-loop x2
// unrolled so LDS ping-pong bases are compile-time.

typedef _Float16 half8 __attribute__((ext_vector_type(8)));
typedef float floatx4 __attribute__((ext_vector_type(4)));

#define LOG2E 1.44269504088896340736f

__global__ __launch_bounds__(512, 4) void lstm_fused(
    const float* __restrict__ x,    // [B,T,C]
    const float* __restrict__ Wih,  // [C,4H]
    const float* __restrict__ Whh,  // [C,4H,H]
    const float* __restrict__ bih,  // [C,4H]
    const float* __restrict__ bhh,  // [C,4H]
    const float* __restrict__ Wfc,  // [C,H]
    const float* __restrict__ bfc,  // [C]
    float* __restrict__ out)        // [B,C]
{
    constexpr int T = 1024, C = 64, H = 128, G = 512;
    constexpr int TC = T * C;

    // Two h buffers: [4 rowtiles][4 ksteps][64 chunks][8 f16] = 8192 f16 = 16 KB each.
    __shared__ _Float16 hbuf[2][8192];

    const int bid = blockIdx.x;
    const int ch  = bid & 63;          // channel
    const int b0  = (bid >> 6) << 6;   // batch tile base: 0,64,...,448

    const int tid = threadIdx.x;
    const int w   = tid >> 6;          // wave 0..7 -> hidden slice [w*16, w*16+16)
    const int l   = tid & 63;
    const int q   = l >> 4;            // quad
    const int li  = l & 15;

    // ---- per-lane constants: W_ih, bias, W_hh fragments in registers ----
    float wihr[4], bias[4];
    half8 Wf[4][4];
#pragma unroll
    for (int ct = 0; ct < 4; ++ct) {
        const float sc = (ct == 2) ? 2.0f * LOG2E : LOG2E;  // gate order i,f,g,o
        const int col = ct * H + w * 16 + li;
        wihr[ct] = Wih[ch * G + col] * sc;
        bias[ct] = (bih[ch * G + col] + bhh[ch * G + col]) * sc;
#pragma unroll
        for (int ks = 0; ks < 4; ++ks) {
            const float* wp = &Whh[((size_t)(ch * G + col)) * H + ks * 32 + q * 8];
            half8 hv;
#pragma unroll
            for (int j = 0; j < 8; ++j) hv[j] = (_Float16)(wp[j] * sc);
            Wf[ct][ks] = hv;
        }
    }

    // zero t=0 read buffer (h0 = 0)
    for (int i = tid; i < 8192; i += 512) hbuf[0][i] = (_Float16)0.0f;

    // cell state (fp32 registers): 4 rowtiles x 4 rows
    float cst[4][4];
#pragma unroll
    for (int rt = 0; rt < 4; ++rt)
#pragma unroll
        for (int r = 0; r < 4; ++r) cst[rt][r] = 0.0f;

    // ---- h layout with XOR bank swizzle ----
    // value (batch row m in tile, hidden hh): ks=hh>>5, qq=(hh&31)>>3, j=hh&7
    // chunk c = qq*16 + (m ^ (qq&3)); element = (rt*4+ks)*512 + c*8 + j
    const int ks_w = w >> 1;
    const int qq_w = ((w & 1) << 1) + (li >> 3);
    const int j_w  = li & 7;
    const int rxor = qq_w & 3;
    // write element offsets per r (row m = q*4 + r):  (q*4+r) ^ rxor == q*4 + (r^rxor)
    int wel[4];
#pragma unroll
    for (int r = 0; r < 4; ++r)
        wel[r] = ks_w * 512 + (qq_w * 16 + q * 4 + (r ^ rxor)) * 8 + j_w;
    // read: lane l wants chunk (qq=q, m=li) -> c = q*16 + (li ^ (q&3))
    const int rdoff = (q * 16 + (li ^ (q & 3))) * 8;

    // ---- x addressing: uniform base pointer + per-lane 32-bit offset ----
    const float* xb = x + ch;
    const int rb0 = (b0 + q * 4) * TC;  // per-lane element offset base

    float xv[4][4];
#pragma unroll
    for (int rt = 0; rt < 4; ++rt)
#pragma unroll
        for (int r = 0; r < 4; ++r)
            xv[rt][r] = xb[rb0 + (rt * 16 + r) * TC];  // t = 0

    const float* xnp   = xb + C;              // next-step base (t=1)
    const float* xlast = xb + (T - 1) * C;

    __syncthreads();

    auto step = [&](const _Float16* __restrict__ rb, _Float16* __restrict__ wb) {
#pragma unroll
        for (int rt = 0; rt < 4; ++rt) {
            // A fragments of previous h (conflict-free b128, swizzled chunks)
            const half8 a0 = *(const half8*)&rb[(rt * 4 + 0) * 512 + rdoff];
            const half8 a1 = *(const half8*)&rb[(rt * 4 + 1) * 512 + rdoff];
            const half8 a2 = *(const half8*)&rb[(rt * 4 + 2) * 512 + rdoff];
            const half8 a3 = *(const half8*)&rb[(rt * 4 + 3) * 512 + rdoff];

            floatx4 acc[4];
#pragma unroll
            for (int ct = 0; ct < 4; ++ct)
                acc[ct] = floatx4{bias[ct], bias[ct], bias[ct], bias[ct]};

#pragma unroll
            for (int ct = 0; ct < 4; ++ct) {
                acc[ct] = __builtin_amdgcn_mfma_f32_16x16x32_f16(a0, Wf[ct][0], acc[ct], 0, 0, 0);
                acc[ct] = __builtin_amdgcn_mfma_f32_16x16x32_f16(a1, Wf[ct][1], acc[ct], 0, 0, 0);
                acc[ct] = __builtin_amdgcn_mfma_f32_16x16x32_f16(a2, Wf[ct][2], acc[ct], 0, 0, 0);
                acc[ct] = __builtin_amdgcn_mfma_f32_16x16x32_f16(a3, Wf[ct][3], acc[ct], 0, 0, 0);
            }

            // x*W_ih added after MFMA chain (gives the x prefetch latency slack)
#pragma unroll
            for (int ct = 0; ct < 4; ++ct)
#pragma unroll
                for (int r = 0; r < 4; ++r)
                    acc[ct][r] = fmaf(xv[rt][r], wihr[ct], acc[ct][r]);

            // activations + state update + swizzled h write (pre-scaled by log2e)
#pragma unroll
            for (int r = 0; r < 4; ++r) {
                const float ig = __builtin_amdgcn_rcpf(1.0f + __builtin_amdgcn_exp2f(-acc[0][r]));
                const float fg = __builtin_amdgcn_rcpf(1.0f + __builtin_amdgcn_exp2f(-acc[1][r]));
                const float gg = 1.0f - 2.0f * __builtin_amdgcn_rcpf(1.0f + __builtin_amdgcn_exp2f(acc[2][r]));
                const float og = __builtin_amdgcn_rcpf(1.0f + __builtin_amdgcn_exp2f(-acc[3][r]));
                const float cn = fg * cst[rt][r] + ig * gg;
                cst[rt][r] = cn;
                const float tc = 1.0f - 2.0f * __builtin_amdgcn_rcpf(
                                     1.0f + __builtin_amdgcn_exp2f(cn * (2.0f * LOG2E)));
                wb[rt * 2048 + wel[r]] = (_Float16)(og * tc);
            }
        }

        // reload xv for the NEXT step (same registers -> prefetch across barrier)
#pragma unroll
        for (int rt = 0; rt < 4; ++rt)
#pragma unroll
            for (int r = 0; r < 4; ++r)
                xv[rt][r] = xnp[rb0 + (rt * 16 + r) * TC];

        __syncthreads();
    };

    for (int t = 0; t < T; t += 2) {
        step(hbuf[0], hbuf[1]);
        xnp = (xnp == xlast) ? xnp : xnp + C;
        step(hbuf[1], hbuf[0]);
        xnp = (xnp == xlast) ? xnp : xnp + C;
    }

    // ---- epilogue: out[b0+row, ch] = h_final . Wfc[ch] + bfc[ch] ----
    // t=1023 wrote hbuf[0] (last step call writes hbuf[0]); final barrier done.
    if (tid < 64) {
        const int row = tid;
        const int rt = row >> 4, m = row & 15;
        float s = bfc[ch];
#pragma unroll
        for (int hh = 0; hh < H; ++hh) {
            const int ks = hh >> 5, qq = (hh & 31) >> 3, j = hh & 7;
            const int c = qq * 16 + (m ^ (qq & 3));
            s += (float)hbuf[0][(rt * 4 + ks) * 512 + c * 8 + j] * Wfc[ch * H + hh];
        }
        out[(size_t)(b0 + row) * C + ch] = s;
    }
}

extern "C" void kernel_launch(void* const* d_in, const int* in_sizes, int n_in,
                              void* d_out, int out_size, void* d_ws, size_t ws_size,
                              hipStream_t stream) {
    const float* x   = (const float*)d_in[0];
    const float* Wih = (const float*)d_in[1];
    const float* Whh = (const float*)d_in[2];
    const float* bih = (const float*)d_in[3];
    const float* bhh = (const float*)d_in[4];
    const float* Wfc = (const float*)d_in[5];
    const float* bfc = (const float*)d_in[6];
    float* out = (float*)d_out;

    lstm_fused<<<512, 512, 0, stream>>>(x, Wih, Whh, bih, bhh, Wfc, bfc, out);
}

// Round 3
// 6371.164 us; speedup vs baseline: 4.5470x; 4.5470x over previous
//
#include <hip/hip_runtime.h>

// Per-channel LSTM (input_size=1) + per-channel Linear(H,1), fully fused.
// B=512, T=1024, C=64, H=128.
// Round 3: R2 structure (grid=512, 64-row tiles, 32KB LDS, XOR swizzle,
// x prefetch across barrier) but launch_bounds(512,2): empirically the
// compiler's VGPR budget = 256 / min_waves_per_EU, so (512,4) clamped to
// 64 VGPRs and spilled 120 GB to scratch (R2 post-mortem). (512,2) -> 128
// budget, fits; HW then co-schedules 2 blocks/CU (16 waves x 128 VGPR).
// Also: single live A-fragment (4 MFMAs per ds_read) and bias folded into
// the x-fma init to cut peak register pressure and v_movs.

typedef _Float16 half8 __attribute__((ext_vector_type(8)));
typedef float floatx4 __attribute__((ext_vector_type(4)));

#define LOG2E 1.44269504088896340736f

__global__ __launch_bounds__(512, 2) void lstm_fused(
    const float* __restrict__ x,    // [B,T,C]
    const float* __restrict__ Wih,  // [C,4H]
    const float* __restrict__ Whh,  // [C,4H,H]
    const float* __restrict__ bih,  // [C,4H]
    const float* __restrict__ bhh,  // [C,4H]
    const float* __restrict__ Wfc,  // [C,H]
    const float* __restrict__ bfc,  // [C]
    float* __restrict__ out)        // [B,C]
{
    constexpr int T = 1024, C = 64, H = 128, G = 512;
    constexpr int TC = T * C;

    // Two h buffers: [4 rowtiles][4 ksteps][64 chunks][8 f16] = 16 KB each.
    __shared__ _Float16 hbuf[2][8192];

    const int bid = blockIdx.x;
    const int ch  = bid & 63;          // channel
    const int b0  = (bid >> 6) << 6;   // batch tile base: 0,64,...,448

    const int tid = threadIdx.x;
    const int w   = tid >> 6;          // wave 0..7 -> hidden slice [w*16, w*16+16)
    const int l   = tid & 63;
    const int q   = l >> 4;            // quad
    const int li  = l & 15;

    // ---- per-lane constants: W_ih, bias, W_hh fragments in registers ----
    float wihr[4], bias[4];
    half8 Wf[4][4];
#pragma unroll
    for (int ct = 0; ct < 4; ++ct) {
        const float sc = (ct == 2) ? 2.0f * LOG2E : LOG2E;  // gate order i,f,g,o
        const int col = ct * H + w * 16 + li;
        wihr[ct] = Wih[ch * G + col] * sc;
        bias[ct] = (bih[ch * G + col] + bhh[ch * G + col]) * sc;
#pragma unroll
        for (int ks = 0; ks < 4; ++ks) {
            const float* wp = &Whh[((size_t)(ch * G + col)) * H + ks * 32 + q * 8];
            half8 hv;
#pragma unroll
            for (int j = 0; j < 8; ++j) hv[j] = (_Float16)(wp[j] * sc);
            Wf[ct][ks] = hv;
        }
    }

    // zero t=0 read buffer (h0 = 0)
    for (int i = tid; i < 8192; i += 512) hbuf[0][i] = (_Float16)0.0f;

    // cell state (fp32 registers): 4 rowtiles x 4 rows
    float cst[4][4];
#pragma unroll
    for (int rt = 0; rt < 4; ++rt)
#pragma unroll
        for (int r = 0; r < 4; ++r) cst[rt][r] = 0.0f;

    // ---- h layout with XOR bank swizzle ----
    // value (batch row m in tile, hidden hh): ks=hh>>5, qq=(hh&31)>>3, j=hh&7
    // chunk c = qq*16 + (m ^ (qq&3)); element = (rt*4+ks)*512 + c*8 + j
    const int ks_w = w >> 1;
    const int qq_w = ((w & 1) << 1) + (li >> 3);
    const int j_w  = li & 7;
    const int rxor = qq_w & 3;
    int wel[4];
#pragma unroll
    for (int r = 0; r < 4; ++r)
        wel[r] = ks_w * 512 + (qq_w * 16 + q * 4 + (r ^ rxor)) * 8 + j_w;
    // read: lane l wants chunk (qq=q, m=li) -> c = q*16 + (li ^ (q&3))
    const int rdoff = (q * 16 + (li ^ (q & 3))) * 8;

    // ---- x addressing: uniform base pointer + per-lane 32-bit offset ----
    const float* xb = x + ch;
    const int rb0 = (b0 + q * 4) * TC;  // per-lane element offset base

    float xv[4][4];
#pragma unroll
    for (int rt = 0; rt < 4; ++rt)
#pragma unroll
        for (int r = 0; r < 4; ++r)
            xv[rt][r] = xb[rb0 + (rt * 16 + r) * TC];  // t = 0

    const float* xnp   = xb + C;              // next-step base (t=1)
    const float* xlast = xb + (T - 1) * C;

    __syncthreads();

    auto step = [&](const _Float16* __restrict__ rb, _Float16* __restrict__ wb) {
#pragma unroll
        for (int rt = 0; rt < 4; ++rt) {
            // init acc with x*W_ih + bias (one fma each, no movs)
            floatx4 acc[4];
#pragma unroll
            for (int ct = 0; ct < 4; ++ct)
#pragma unroll
                for (int r = 0; r < 4; ++r)
                    acc[ct][r] = fmaf(xv[rt][r], wihr[ct], bias[ct]);

            // one A-fragment live at a time: ds_read_b128 then its 4 MFMAs
#pragma unroll
            for (int ks = 0; ks < 4; ++ks) {
                const half8 a = *(const half8*)&rb[(rt * 4 + ks) * 512 + rdoff];
#pragma unroll
                for (int ct = 0; ct < 4; ++ct)
                    acc[ct] = __builtin_amdgcn_mfma_f32_16x16x32_f16(a, Wf[ct][ks], acc[ct], 0, 0, 0);
            }

            // activations + state update + swizzled h write (pre-scaled by log2e)
#pragma unroll
            for (int r = 0; r < 4; ++r) {
                const float ig = __builtin_amdgcn_rcpf(1.0f + __builtin_amdgcn_exp2f(-acc[0][r]));
                const float fg = __builtin_amdgcn_rcpf(1.0f + __builtin_amdgcn_exp2f(-acc[1][r]));
                const float gg = 1.0f - 2.0f * __builtin_amdgcn_rcpf(1.0f + __builtin_amdgcn_exp2f(acc[2][r]));
                const float og = __builtin_amdgcn_rcpf(1.0f + __builtin_amdgcn_exp2f(-acc[3][r]));
                const float cn = fg * cst[rt][r] + ig * gg;
                cst[rt][r] = cn;
                const float tc = 1.0f - 2.0f * __builtin_amdgcn_rcpf(
                                     1.0f + __builtin_amdgcn_exp2f(cn * (2.0f * LOG2E)));
                wb[rt * 2048 + wel[r]] = (_Float16)(og * tc);
            }
        }

        // reload xv for the NEXT step (same registers -> prefetch across barrier)
#pragma unroll
        for (int rt = 0; rt < 4; ++rt)
#pragma unroll
            for (int r = 0; r < 4; ++r)
                xv[rt][r] = xnp[rb0 + (rt * 16 + r) * TC];

        __syncthreads();
    };

    for (int t = 0; t < T; t += 2) {
        step(hbuf[0], hbuf[1]);
        xnp = (xnp == xlast) ? xnp : xnp + C;
        step(hbuf[1], hbuf[0]);
        xnp = (xnp == xlast) ? xnp : xnp + C;
    }

    // ---- epilogue: out[b0+row, ch] = h_final . Wfc[ch] + bfc[ch] ----
    // T even -> final h is in hbuf[0]; last __syncthreads already done.
    if (tid < 64) {
        const int row = tid;
        const int rt = row >> 4, m = row & 15;
        float s = bfc[ch];
#pragma unroll
        for (int hh = 0; hh < H; ++hh) {
            const int ks = hh >> 5, qq = (hh & 31) >> 3, j = hh & 7;
            const int c = qq * 16 + (m ^ (qq & 3));
            s += (float)hbuf[0][(rt * 4 + ks) * 512 + c * 8 + j] * Wfc[ch * H + hh];
        }
        out[(size_t)(b0 + row) * C + ch] = s;
    }
}

extern "C" void kernel_launch(void* const* d_in, const int* in_sizes, int n_in,
                              void* d_out, int out_size, void* d_ws, size_t ws_size,
                              hipStream_t stream) {
    const float* x   = (const float*)d_in[0];
    const float* Wih = (const float*)d_in[1];
    const float* Whh = (const float*)d_in[2];
    const float* bih = (const float*)d_in[3];
    const float* bhh = (const float*)d_in[4];
    const float* Wfc = (const float*)d_in[5];
    const float* bfc = (const float*)d_in[6];
    float* out = (float*)d_out;

    lstm_fused<<<512, 512, 0, stream>>>(x, Wih, Whh, bih, bhh, Wfc, bfc, out);
}

// Round 4
// 6165.268 us; speedup vs baseline: 4.6988x; 1.0334x over previous
//
#include <hip/hip_runtime.h>

// Per-channel LSTM (input_size=1) + per-channel Linear(H,1), fully fused.
// B=512, T=1024, C=64, H=128.
// Round 4: the kernel is transcendental-pipe-bound (R3: 10 trans/cell at
// ~32 cyc each = 4.2 ms of the 6.4 ms dur). Merge reciprocals: ONE rcp for
// all 4 gate denominators per cell (reconstruct sigmoids/tanh(g) by
// multiplication), and ONE rcp per 4 rows for tanh(c) (exp2 arg clamped to
// +-29 via fmed3 so the 4-product can't overflow; tanh saturates to 1.0f).
// 10 -> 5.25 trans/cell; +~12 mul/fma on the underutilized main VALU pipe.
// Structure otherwise identical to R3 (grid=512, 64-row tiles, 32KB LDS,
// XOR swizzle, x prefetch across barrier, launch_bounds(512,2)).

typedef _Float16 half8 __attribute__((ext_vector_type(8)));
typedef float floatx4 __attribute__((ext_vector_type(4)));

#define LOG2E 1.44269504088896340736f

__global__ __launch_bounds__(512, 2) void lstm_fused(
    const float* __restrict__ x,    // [B,T,C]
    const float* __restrict__ Wih,  // [C,4H]
    const float* __restrict__ Whh,  // [C,4H,H]
    const float* __restrict__ bih,  // [C,4H]
    const float* __restrict__ bhh,  // [C,4H]
    const float* __restrict__ Wfc,  // [C,H]
    const float* __restrict__ bfc,  // [C]
    float* __restrict__ out)        // [B,C]
{
    constexpr int T = 1024, C = 64, H = 128, G = 512;
    constexpr int TC = T * C;

    // Two h buffers: [4 rowtiles][4 ksteps][64 chunks][8 f16] = 16 KB each.
    __shared__ _Float16 hbuf[2][8192];

    const int bid = blockIdx.x;
    const int ch  = bid & 63;          // channel
    const int b0  = (bid >> 6) << 6;   // batch tile base: 0,64,...,448

    const int tid = threadIdx.x;
    const int w   = tid >> 6;          // wave 0..7 -> hidden slice [w*16, w*16+16)
    const int l   = tid & 63;
    const int q   = l >> 4;            // quad
    const int li  = l & 15;

    // ---- per-lane constants: W_ih, bias, W_hh fragments in registers ----
    float wihr[4], bias[4];
    half8 Wf[4][4];
#pragma unroll
    for (int ct = 0; ct < 4; ++ct) {
        const float sc = (ct == 2) ? 2.0f * LOG2E : LOG2E;  // gate order i,f,g,o
        const int col = ct * H + w * 16 + li;
        wihr[ct] = Wih[ch * G + col] * sc;
        bias[ct] = (bih[ch * G + col] + bhh[ch * G + col]) * sc;
#pragma unroll
        for (int ks = 0; ks < 4; ++ks) {
            const float* wp = &Whh[((size_t)(ch * G + col)) * H + ks * 32 + q * 8];
            half8 hv;
#pragma unroll
            for (int j = 0; j < 8; ++j) hv[j] = (_Float16)(wp[j] * sc);
            Wf[ct][ks] = hv;
        }
    }

    // zero t=0 read buffer (h0 = 0)
    for (int i = tid; i < 8192; i += 512) hbuf[0][i] = (_Float16)0.0f;

    // cell state (fp32 registers): 4 rowtiles x 4 rows
    float cst[4][4];
#pragma unroll
    for (int rt = 0; rt < 4; ++rt)
#pragma unroll
        for (int r = 0; r < 4; ++r) cst[rt][r] = 0.0f;

    // ---- h layout with XOR bank swizzle ----
    // value (batch row m in tile, hidden hh): ks=hh>>5, qq=(hh&31)>>3, j=hh&7
    // chunk c = qq*16 + (m ^ (qq&3)); element = (rt*4+ks)*512 + c*8 + j
    const int ks_w = w >> 1;
    const int qq_w = ((w & 1) << 1) + (li >> 3);
    const int j_w  = li & 7;
    const int rxor = qq_w & 3;
    int wel[4];
#pragma unroll
    for (int r = 0; r < 4; ++r)
        wel[r] = ks_w * 512 + (qq_w * 16 + q * 4 + (r ^ rxor)) * 8 + j_w;
    // read: lane l wants chunk (qq=q, m=li) -> c = q*16 + (li ^ (q&3))
    const int rdoff = (q * 16 + (li ^ (q & 3))) * 8;

    // ---- x addressing: uniform base pointer + per-lane 32-bit offset ----
    const float* xb = x + ch;
    const int rb0 = (b0 + q * 4) * TC;  // per-lane element offset base

    float xv[4][4];
#pragma unroll
    for (int rt = 0; rt < 4; ++rt)
#pragma unroll
        for (int r = 0; r < 4; ++r)
            xv[rt][r] = xb[rb0 + (rt * 16 + r) * TC];  // t = 0

    const float* xnp   = xb + C;              // next-step base (t=1)
    const float* xlast = xb + (T - 1) * C;

    __syncthreads();

    auto step = [&](const _Float16* __restrict__ rb, _Float16* __restrict__ wb) {
#pragma unroll
        for (int rt = 0; rt < 4; ++rt) {
            // init acc with x*W_ih + bias (one fma each)
            floatx4 acc[4];
#pragma unroll
            for (int ct = 0; ct < 4; ++ct)
#pragma unroll
                for (int r = 0; r < 4; ++r)
                    acc[ct][r] = fmaf(xv[rt][r], wihr[ct], bias[ct]);

            // one A-fragment live at a time: ds_read_b128 then its 4 MFMAs
#pragma unroll
            for (int ks = 0; ks < 4; ++ks) {
                const half8 a = *(const half8*)&rb[(rt * 4 + ks) * 512 + rdoff];
#pragma unroll
                for (int ct = 0; ct < 4; ++ct)
                    acc[ct] = __builtin_amdgcn_mfma_f32_16x16x32_f16(a, Wf[ct][ks], acc[ct], 0, 0, 0);
            }

            // ---- activations, merged reciprocals ----
            // gates (prescaled by log2e; g by 2*log2e):
            //   u=2^-ti, v=2^-tf, p=2^tg, wq=2^-to
            //   sig_i=1/(1+u), sig_f=1/(1+v), tanh_g=1-2/(1+p), sig_o=1/(1+wq)
            // One rcp of the 4-denominator product reconstructs all four.
            // |preact|<=~12 -> product <= ~3e26, no overflow.
            float cn[4], og[4];
#pragma unroll
            for (int r = 0; r < 4; ++r) {
                const float u  = __builtin_amdgcn_exp2f(-acc[0][r]);
                const float v  = __builtin_amdgcn_exp2f(-acc[1][r]);
                const float p  = __builtin_amdgcn_exp2f(acc[2][r]);
                const float wq = __builtin_amdgcn_exp2f(-acc[3][r]);
                const float Du = 1.0f + u, Dv = 1.0f + v;
                const float Dp = 1.0f + p, Dw = 1.0f + wq;
                const float A  = Du * Dv, Bq = Dp * Dw;
                const float R  = __builtin_amdgcn_rcpf(A * Bq);
                const float RA = R * Bq;              // = 1/(Du*Dv)
                const float RB = R * A;               // = 1/(Dp*Dw)
                const float ig = Dv * RA;             // sigmoid(i)
                const float fg = Du * RA;             // sigmoid(f)
                const float gg = fmaf(-2.0f, Dw * RB, 1.0f);  // tanh(g)
                og[r] = Dp * RB;                      // sigmoid(o)
                cn[r] = fmaf(fg, cst[rt][r], ig * gg);
                cst[rt][r] = cn[r];
            }
            // tanh(cn) for 4 rows with ONE rcp; clamp exp2 arg to +-29 so the
            // 4-product stays finite (tanh(29/(2*log2e)) rounds to 1.0f).
            float Dq[4];
#pragma unroll
            for (int r = 0; r < 4; ++r) {
                const float t = __builtin_amdgcn_fmed3f(
                    cn[r] * (2.0f * LOG2E), -29.0f, 29.0f);
                Dq[r] = 1.0f + __builtin_amdgcn_exp2f(t);
            }
            const float P01 = Dq[0] * Dq[1], P23 = Dq[2] * Dq[3];
            const float Rq  = __builtin_amdgcn_rcpf(P01 * P23);
            const float R23 = Rq * P23, R01 = Rq * P01;
            const float iq0 = R23 * Dq[1], iq1 = R23 * Dq[0];
            const float iq2 = R01 * Dq[3], iq3 = R01 * Dq[2];
            wb[rt * 2048 + wel[0]] = (_Float16)(og[0] * fmaf(-2.0f, iq0, 1.0f));
            wb[rt * 2048 + wel[1]] = (_Float16)(og[1] * fmaf(-2.0f, iq1, 1.0f));
            wb[rt * 2048 + wel[2]] = (_Float16)(og[2] * fmaf(-2.0f, iq2, 1.0f));
            wb[rt * 2048 + wel[3]] = (_Float16)(og[3] * fmaf(-2.0f, iq3, 1.0f));
        }

        // reload xv for the NEXT step (same registers -> prefetch across barrier)
#pragma unroll
        for (int rt = 0; rt < 4; ++rt)
#pragma unroll
            for (int r = 0; r < 4; ++r)
                xv[rt][r] = xnp[rb0 + (rt * 16 + r) * TC];

        __syncthreads();
    };

    for (int t = 0; t < T; t += 2) {
        step(hbuf[0], hbuf[1]);
        xnp = (xnp == xlast) ? xnp : xnp + C;
        step(hbuf[1], hbuf[0]);
        xnp = (xnp == xlast) ? xnp : xnp + C;
    }

    // ---- epilogue: out[b0+row, ch] = h_final . Wfc[ch] + bfc[ch] ----
    // T even -> final h is in hbuf[0]; last __syncthreads already done.
    if (tid < 64) {
        const int row = tid;
        const int rt = row >> 4, m = row & 15;
        float s = bfc[ch];
#pragma unroll
        for (int hh = 0; hh < H; ++hh) {
            const int ks = hh >> 5, qq = (hh & 31) >> 3, j = hh & 7;
            const int c = qq * 16 + (m ^ (qq & 3));
            s += (float)hbuf[0][(rt * 4 + ks) * 512 + c * 8 + j] * Wfc[ch * H + hh];
        }
        out[(size_t)(b0 + row) * C + ch] = s;
    }
}

extern "C" void kernel_launch(void* const* d_in, const int* in_sizes, int n_in,
                              void* d_out, int out_size, void* d_ws, size_t ws_size,
                              hipStream_t stream) {
    const float* x   = (const float*)d_in[0];
    const float* Wih = (const float*)d_in[1];
    const float* Whh = (const float*)d_in[2];
    const float* bih = (const float*)d_in[3];
    const float* bhh = (const float*)d_in[4];
    const float* Wfc = (const float*)d_in[5];
    const float* bfc = (const float*)d_in[6];
    float* out = (float*)d_out;

    lstm_fused<<<512, 512, 0, stream>>>(x, Wih, Whh, bih, bhh, Wfc, bfc, out);
}